// Round 2
// baseline (161.463 us; speedup 1.0000x reference)
//
#include <hip/hip_runtime.h>
#include <stdint.h>

#define N_NODES   4096
#define N_EDGES   128
#define D_X       128
#define PE_DIM    64
#define NUM_WALKS 10
#define WALK_LEN  5
#define N_WALKS_TOT (N_NODES * NUM_WALKS)   /* 40960 */
#define OUT_COLS  (D_X + PE_DIM)            /* 192 */
#define OUT_TOT   (N_NODES * OUT_COLS)      /* 786432 */
#define ADJ_CAP   (1310720u)                /* u16 entries; expected ~840K used */

/* workspace layout (bytes) */
#define OFF_MASKS   0u                                   /* 4096 * 16 = 65536 */
#define OFF_DEG     (OFF_MASKS + N_NODES * 16u)          /* 16384 */
#define OFF_ROWPTR  (OFF_DEG + N_NODES * 4u)             /* (N+1)*4 -> pad 16640 */
#define OFF_ADJ     (OFF_ROWPTR + 16640u)                /* ADJ_CAP*2 = 2.5 MiB */
#define OFF_PE      (OFF_ADJ + ADJ_CAP * 2u)             /* 4096*64*4 = 1 MiB */
#define OFF_CNT     (OFF_PE + N_NODES * PE_DIM * 4u)     /* 16384 */

/* ---- JAX threefry2x32 (20 rounds) ---- */
__device__ __forceinline__ void tf2x32(uint32_t kk0, uint32_t kk1,
                                       uint32_t x0, uint32_t x1,
                                       uint32_t& o0, uint32_t& o1) {
  const uint32_t kk2 = kk0 ^ kk1 ^ 0x1BD11BDAu;
  x0 += kk0; x1 += kk1;
  auto rnd = [&](int r) {
    x0 += x1;
    x1 = (x1 << r) | (x1 >> (32 - r));
    x1 ^= x0;
  };
  rnd(13); rnd(15); rnd(26); rnd(6);   x0 += kk1; x1 += kk2 + 1u;
  rnd(17); rnd(29); rnd(16); rnd(24);  x0 += kk2; x1 += kk0 + 2u;
  rnd(13); rnd(15); rnd(26); rnd(6);   x0 += kk0; x1 += kk1 + 3u;
  rnd(17); rnd(29); rnd(16); rnd(24);  x0 += kk1; x1 += kk2 + 4u;
  rnd(13); rnd(15); rnd(26); rnd(6);   x0 += kk2; x1 += kk0 + 5u;
  o0 = x0; o1 = x1;
}

/* ---- K1: 128-bit incidence masks (one wave per node) ---- */
__global__ void k_masks(const float* __restrict__ inc,
                        ulonglong2* __restrict__ masks) {
  const int wid = threadIdx.x >> 6, lane = threadIdx.x & 63;
  const int i = blockIdx.x * 4 + wid;
  const float a = inc[i * N_EDGES + lane];
  const float b = inc[i * N_EDGES + 64 + lane];
  const unsigned long long m0 = __ballot(a != 0.f);
  const unsigned long long m1 = __ballot(b != 0.f);
  if (lane == 0) masks[i] = make_ulonglong2(m0, m1);
}

/* ---- K2: degree per node (self excluded) ---- */
__global__ void k_degree(const ulonglong2* __restrict__ masks,
                         unsigned int* __restrict__ deg) {
  const int wid = threadIdx.x >> 6, lane = threadIdx.x & 63;
  const int i = blockIdx.x * 4 + wid;
  const ulonglong2 mi = masks[i];
  unsigned int c = 0;
  for (int g = 0; g < N_NODES / 64; ++g) {
    const int j = g * 64 + lane;
    const ulonglong2 mj = masks[j];
    const bool pred = (((mi.x & mj.x) | (mi.y & mj.y)) != 0ull) && (j != i);
    c += (unsigned int)__popcll(__ballot(pred));
  }
  if (lane == 0) deg[i] = c;
}

/* ---- K3: single-block prefix scan of 4096 degrees -> rowptr ---- */
__global__ void k_scan(const unsigned int* __restrict__ deg,
                       unsigned int* __restrict__ rowptr) {
  __shared__ unsigned int sh[1024];
  const int t = threadIdx.x;
  const unsigned int e0 = deg[4 * t], e1 = deg[4 * t + 1],
                     e2 = deg[4 * t + 2], e3 = deg[4 * t + 3];
  const unsigned int p0 = e0, p1 = p0 + e1, p2 = p1 + e2, p3 = p2 + e3;
  sh[t] = p3;
  __syncthreads();
  for (int off = 1; off < 1024; off <<= 1) {
    const unsigned int v = sh[t];
    const unsigned int add = (t >= off) ? sh[t - off] : 0u;
    __syncthreads();
    sh[t] = v + add;
    __syncthreads();
  }
  const unsigned int base = sh[t] - p3; /* exclusive prefix */
  if (t == 0) rowptr[0] = 0u;
  rowptr[4 * t + 1] = base + p0;
  rowptr[4 * t + 2] = base + p1;
  rowptr[4 * t + 3] = base + p2;
  rowptr[4 * t + 4] = base + p3;
}

/* ---- K4: fill adjacency (ascending j per node) ---- */
__global__ void k_fill(const ulonglong2* __restrict__ masks,
                       const unsigned int* __restrict__ rowptr,
                       unsigned short* __restrict__ adj) {
  const int wid = threadIdx.x >> 6, lane = threadIdx.x & 63;
  const int i = blockIdx.x * 4 + wid;
  const ulonglong2 mi = masks[i];
  unsigned int base = rowptr[i];
  for (int g = 0; g < N_NODES / 64; ++g) {
    const int j = g * 64 + lane;
    const ulonglong2 mj = masks[j];
    const bool pred = (((mi.x & mj.x) | (mi.y & mj.y)) != 0ull) && (j != i);
    const unsigned long long bal = __ballot(pred);
    if (pred) {
      const unsigned int off =
          (unsigned int)__popcll(bal & ((1ull << lane) - 1ull));
      const unsigned int pos = base + off;
      if (pos < ADJ_CAP) adj[pos] = (unsigned short)j;
    }
    base += (unsigned int)__popcll(bal);
  }
}

/* ---- K5: walks + mean embedding + scatter (one wave per walk) ---- */
__global__ void __launch_bounds__(256)
k_walk(const unsigned int* __restrict__ rowptr,
       const unsigned short* __restrict__ adj,
       const float* __restrict__ embed,
       float* __restrict__ pe_sum, unsigned int* __restrict__ cnt) {
  const int wid = threadIdx.x >> 6, lane = threadIdx.x & 63;
  const int w = blockIdx.x * 4 + wid;

  /* step keys: fold-like split of base key (0,42); constant-folds at -O3 */
  uint32_t k0[4], k1[4];
#pragma unroll
  for (int t = 0; t < 4; ++t) tf2x32(0u, 42u, 0u, (uint32_t)t, k0[t], k1[t]);

  uint32_t nodes[WALK_LEN];
  nodes[0] = (uint32_t)(w / NUM_WALKS);
  uint32_t validbits = 1u;
  bool alive = true;
  uint32_t cur = nodes[0];

#pragma unroll
  for (int t = 0; t < WALK_LEN - 1; ++t) {
    const unsigned int rb = rowptr[cur];
    unsigned int degc = rowptr[cur + 1] - rb;
    if (rb + degc > ADJ_CAP) degc = (rb < ADJ_CAP) ? (ADJ_CAP - rb) : 0u;
    alive = alive && (degc > 0);
    if (alive) {
      unsigned long long best = 0ull;
      for (unsigned int s = lane; s < degc; s += 64) {
        const uint32_t n = adj[rb + s];
        uint32_t o0, o1;
        tf2x32(k0[t], k1[t], 0u, (uint32_t)w * (uint32_t)N_NODES + n, o0, o1);
        const uint32_t val = (o0 ^ o1) >> 9; /* monotone proxy for gumbel */
        const unsigned long long cand =
            ((unsigned long long)val << 16) | (unsigned long long)(65535u - n);
        if (cand > best) best = cand;
      }
#pragma unroll
      for (int d = 32; d >= 1; d >>= 1) {
        const unsigned long long o = __shfl_xor(best, d);
        if (o > best) best = o;
      }
      cur = 65535u - (uint32_t)(best & 0xFFFFull);
      validbits |= (1u << (t + 1));
    }
    nodes[t + 1] = cur;
  }

  /* mean embedding over valid positions; lane == dim (PE_DIM == 64) */
  const int len = __popc(validbits);
  float s = 0.f;
#pragma unroll
  for (int p = 0; p < WALK_LEN; ++p)
    if (validbits & (1u << p)) s += embed[nodes[p] * PE_DIM + lane];
  const float m = s / (float)len;

#pragma unroll
  for (int p = 0; p < WALK_LEN; ++p)
    if (validbits & (1u << p)) {
      atomicAdd(&pe_sum[nodes[p] * PE_DIM + lane], m);
      if (lane == 0) atomicAdd(&cnt[nodes[p]], 1u);
    }
}

/* ---- K6: out = [x | pe_sum/cnt] in f32 ---- */
__global__ void k_out(const float* __restrict__ x,
                      const float* __restrict__ pe_sum,
                      const unsigned int* __restrict__ cnt,
                      float* __restrict__ out) {
  const int idx = blockIdx.x * 256 + threadIdx.x;
  const int i = idx / OUT_COLS;
  const int c = idx - i * OUT_COLS;
  if (c < D_X) {
    out[idx] = x[i * D_X + c];
  } else {
    const int d = c - D_X;
    const unsigned int k = cnt[i];
    out[idx] = (k > 0) ? pe_sum[i * PE_DIM + d] / (float)k : 0.f;
  }
}

extern "C" void kernel_launch(void* const* d_in, const int* in_sizes, int n_in,
                              void* d_out, int out_size, void* d_ws, size_t ws_size,
                              hipStream_t stream) {
  const float* x   = (const float*)d_in[0];
  const float* inc = (const float*)d_in[1];
  const float* emb = (const float*)d_in[2];

  char* ws = (char*)d_ws;
  ulonglong2*     masks  = (ulonglong2*)(ws + OFF_MASKS);
  unsigned int*   deg    = (unsigned int*)(ws + OFF_DEG);
  unsigned int*   rowptr = (unsigned int*)(ws + OFF_ROWPTR);
  unsigned short* adj    = (unsigned short*)(ws + OFF_ADJ);
  float*          pe     = (float*)(ws + OFF_PE);
  unsigned int*   cnt    = (unsigned int*)(ws + OFF_CNT);

  /* pe_sum + cnt are contiguous: zero both each call (graph-capture safe) */
  hipMemsetAsync(pe, 0, (size_t)N_NODES * PE_DIM * 4u + (size_t)N_NODES * 4u,
                 stream);

  k_masks <<<N_NODES / 4, 256, 0, stream>>>(inc, masks);
  k_degree<<<N_NODES / 4, 256, 0, stream>>>(masks, deg);
  k_scan  <<<1, 1024, 0, stream>>>(deg, rowptr);
  k_fill  <<<N_NODES / 4, 256, 0, stream>>>(masks, rowptr, adj);
  k_walk  <<<N_WALKS_TOT / 4, 256, 0, stream>>>(rowptr, adj, emb, pe, cnt);
  k_out   <<<OUT_TOT / 256, 256, 0, stream>>>(x, pe, cnt, (float*)d_out);
}